// Round 12
// baseline (563.163 us; speedup 1.0000x reference)
//
#include <hip/hip_runtime.h>

// Problem constants (fixed by setup_inputs)
#define BB 8
#define CIN 64
#define COUT 64
#define NN 2048
#define TT 13
#define KTT 3
#define LL 11
#define CL 704                         // COUT*LL
#define HP_SIZE 11534336LL             // B*COUT*N*L

// GEMM tiling (32x32x16 MFMA)
#define BM 352                         // 11 m-subtiles of 32
#define BN 128                         // 2 qw x 2 nf x 32
#define A_TILE 11264                   // f16 per BK=32 tile: 2kc x 11msub x 2kh x 32row x 8

// ws layout (bytes): fbuf 65536 | maxf 32 | tab4 262144 | w0pk 24576 | Apan
#define WS_TAB_OFF 65568ULL
#define WS_W0PK_OFF 327712ULL
#define WS_APAN_OFF 352288ULL

typedef _Float16 f16;
typedef __attribute__((ext_vector_type(8))) _Float16 f16x8;
typedef __attribute__((ext_vector_type(2))) _Float16 f16x2;
typedef __attribute__((ext_vector_type(16))) float f32x16;

__device__ __forceinline__ unsigned int pk16(float a, float b) {
  f16 ha = (f16)a, hb = (f16)b;                    // RTN converts
  unsigned short ua = __builtin_bit_cast(unsigned short, ha);
  unsigned short ub = __builtin_bit_cast(unsigned short, hb);
  return (unsigned int)ua | ((unsigned int)ub << 16);
}
__device__ __forceinline__ f16x2 as_h2(unsigned int u) {
  return __builtin_bit_cast(f16x2, u);
}
__device__ __forceinline__ void gl_lds16(const f16* g, f16* l) {
  __builtin_amdgcn_global_load_lds(
      (const __attribute__((address_space(1))) unsigned int*)g,
      (__attribute__((address_space(3))) unsigned int*)l, 16, 0, 0);
}

// ---------------------------------------------------------------------------
// Kernel 0: pack w0 into ci-pair v2f16 form, once.
// ---------------------------------------------------------------------------
__global__ __launch_bounds__(256) void k_pack(const float* __restrict__ w0,
                                              unsigned int* __restrict__ w0pk_g) {
  int tid = blockIdx.x * 256 + threadIdx.x;        // 6144 total
  int c = tid & 63, r = tid >> 6;                  // r = cip*3+kt, 0..95
  int kt = r % 3, cip = r / 3;
  float ev = w0[c * 192 + cip * 6 + kt];
  float od = w0[c * 192 + cip * 6 + 3 + kt];
  w0pk_g[r * 64 + c] = pk16(ev, od);
}

// ---------------------------------------------------------------------------
// Kernel 1: conv0 via v_dot2_f32_f16 -> fp16 A panels (32-row-frag layout) + f.
// A panel: Apan[(b*2+ct)*64+ks][kc2][msub11][kh2][row32][8]  (A_TILE per ks)
// ---------------------------------------------------------------------------
__global__ __launch_bounds__(512, 4) void k_conv(
    const float* __restrict__ x, const unsigned int* __restrict__ w0pk_g,
    const float* __restrict__ b0, const float* __restrict__ w1,
    f16* __restrict__ Apan, float* __restrict__ f) {
  __shared__ unsigned int w0pk[96 * 64];       // 24 KB
  __shared__ unsigned int xspk[32 * 8 * 16];   // 16 KB
  __shared__ f16 As[704 * 10];                 // 14 KB
  const int tid = threadIdx.x;
  const int b = blockIdx.x >> 8;
  const int n0 = (blockIdx.x & 255) << 3;

#pragma unroll
  for (int i = 0; i < 12; ++i) w0pk[i * 512 + tid] = w0pk_g[i * 512 + tid];

#pragma unroll
  for (int i = 0; i < 7; ++i) {
    int task = i * 512 + tid;                  // 3328 total
    if (task < 3328) {
      int cip = task / 104, rem = task - cip * 104;
      long long base = (long long)(b * 64 + 2 * cip) * 26624 + n0 * 13 + rem;
      float ev = x[base];
      float od = x[base + 26624];
      int n = rem / 13, t = rem - n * 13;
      xspk[(cip * 8 + n) * 16 + t] = pk16(ev, od);
    }
  }
  __syncthreads();

  const int c = tid & 63, w = tid >> 6;
  float acc[11];
  const float bias = b0[c];
#pragma unroll
  for (int l = 0; l < 11; ++l) acc[l] = bias;

  for (int cip = 0; cip < 32; ++cip) {
    const unsigned int* xr = &xspk[(cip * 8 + w) * 16];
    uint4 xa = *(const uint4*)xr;
    uint4 xb = *(const uint4*)(xr + 4);
    uint4 xc = *(const uint4*)(xr + 8);
    unsigned int x13[13] = {xa.x, xa.y, xa.z, xa.w, xb.x, xb.y, xb.z, xb.w,
                            xc.x, xc.y, xc.z, xc.w, xr[12]};
    f16x2 wk0 = as_h2(w0pk[(cip * 3 + 0) * 64 + c]);
    f16x2 wk1 = as_h2(w0pk[(cip * 3 + 1) * 64 + c]);
    f16x2 wk2 = as_h2(w0pk[(cip * 3 + 2) * 64 + c]);
#pragma unroll
    for (int l = 0; l < 11; ++l) {
      acc[l] = __builtin_amdgcn_fdot2(as_h2(x13[l]), wk0, acc[l], false);
      acc[l] = __builtin_amdgcn_fdot2(as_h2(x13[l + 1]), wk1, acc[l], false);
      acc[l] = __builtin_amdgcn_fdot2(as_h2(x13[l + 2]), wk2, acc[l], false);
    }
  }

  float p = 0.f;
#pragma unroll
  for (int l = 0; l < 11; ++l) p = fmaf(acc[l], w1[c * 11 + l], p);
#pragma unroll
  for (int off = 32; off; off >>= 1) p += __shfl_xor(p, off, 64);
  if (c == 0) f[b * 2048 + n0 + w] = p;

#pragma unroll
  for (int l = 0; l < 11; ++l) As[(c * 11 + l) * 10 + w] = (f16)acc[l];
  __syncthreads();

  // panel write: this block covers ks, kc=(n0>>4)&1, kh=(n0>>3)&1, kk=0..7
  const int ks = n0 >> 5, kc = (n0 >> 4) & 1, kh = (n0 >> 3) & 1;
  const unsigned int* As32 = (const unsigned int*)As;
#pragma unroll
  for (int i = 0; i < 2; ++i) {
    int m = i * 512 + tid;
    if (m < 704) {
      uint4 v;
      v.x = As32[m * 5 + 0];
      v.y = As32[m * 5 + 1];
      v.z = As32[m * 5 + 2];
      v.w = As32[m * 5 + 3];
      int ct = m / 352, mr = m - ct * 352;
      int msub = mr >> 5, row = m & 31;
      long long base = (long long)((b * 2 + ct) * 64 + ks) * A_TILE +
                       kc * 5632 + msub * 512 + kh * 256 + row * 8;
      *(uint4*)&Apan[base] = v;
    }
  }
}

// ---------------------------------------------------------------------------
// Kernel 2: per-batch max of f
// ---------------------------------------------------------------------------
__global__ __launch_bounds__(256) void k_maxf(const float* __restrict__ f,
                                              float* __restrict__ maxf) {
  const int b = blockIdx.x, tid = threadIdx.x;
  float m = -1e30f;
  for (int i = tid; i < 2048; i += 256) m = fmaxf(m, f[b * 2048 + i]);
#pragma unroll
  for (int off = 32; off; off >>= 1) m = fmaxf(m, __shfl_xor(m, off, 64));
  __shared__ float red[4];
  if ((tid & 63) == 0) red[tid >> 6] = m;
  __syncthreads();
  if (tid == 0) maxf[b] = fmaxf(fmaxf(red[0], red[1]), fmaxf(red[2], red[3]));
}

// ---------------------------------------------------------------------------
// Kernel 3: softmax row sums + exp-factor table tab4 = (En, E2n, Rq, Sq).
// att[n][q] = (fn+fq>=0) ? En_n*Rq_q : E2n_n*Sq_q  (exact factorization)
// ---------------------------------------------------------------------------
__global__ __launch_bounds__(256) void k_rowsum(const float* __restrict__ f,
                                                const float* __restrict__ maxf,
                                                float4* __restrict__ tab4) {
  __shared__ float fs[2048];
  const int b = blockIdx.x >> 9;
  const int q0 = (blockIdx.x & 511) << 2;
  const int tid = threadIdx.x;
#pragma unroll
  for (int i = 0; i < 8; ++i) fs[i * 256 + tid] = f[b * 2048 + i * 256 + tid];
  __syncthreads();
  const int lane = tid & 63, wid = tid >> 6;
  const int q = q0 + wid;
  const float fq = fs[q];
  const float mb = maxf[b];
  float t = fq + mb;
  const float m = t >= 0.f ? t : 0.2f * t;
  float sum = 0.f;
  for (int j = lane; j < 2048; j += 64) {
    float v = fq + fs[j];
    v = v >= 0.f ? v : 0.2f * v;
    sum += __expf(v - m);
  }
#pragma unroll
  for (int off = 32; off; off >>= 1) sum += __shfl_xor(sum, off, 64);
  if (lane == 0) {
    float rq = 1.0f / sum;
    float En = __expf(fq - mb);
    float E2 = __expf(0.2f * fq);
    float Rq = t >= 0.f ? rq : rq * __expf(0.8f * t);
    float Sq = rq * __expf(0.2f * fq - m);
    tab4[b * 2048 + q] = make_float4(En, E2, Rq, Sq);
  }
}

// ---------------------------------------------------------------------------
// Kernel 4: 32x32x16 fp16 MFMA GEMM, counted-vmcnt pipeline, 2 blocks/CU.
// LDS 78 KB: A double-buffer (gl_lds), B double-buffer, Etab float2.
// RACE FIX vs R11: a mid-iteration s_barrier separates compute(ks) (reads
// Abuf[ks&1]) from stageA(ks+2) (refills Abuf[ks&1]) -- all waves' ds_reads
// complete (gated by their consuming MFMAs' lgkm waits) before any wave's
// gl_lds can overwrite the buffer. vmcnt discipline unchanged.
// Fused balanced att stores: lane mask (qb>>5)&1==ct, 8 stores/wave/tile.
// ---------------------------------------------------------------------------
__global__ __launch_bounds__(512, 4) void k_gemm(const f16* __restrict__ Apan,
                                                 const float* __restrict__ f,
                                                 const float* __restrict__ maxf,
                                                 const float4* __restrict__ tab4,
                                                 float* __restrict__ att,
                                                 float* __restrict__ out) {
  __shared__ __align__(16) f16 Abuf[2][A_TILE];        // 45056 B
  __shared__ __align__(16) f16 Bbuf[2][4096];          // 16384 B
  __shared__ __align__(16) float2 Etab[2048];          // 16384 B
  __shared__ __align__(16) f16 Dpad[1024];             //  2048 B (uniformity sink)

  const int p = blockIdx.x;
  const int g = p & 15, qt = p >> 4;              // same-g blocks share an XCD
  const int ct = g & 1, b = g >> 1;

  const int tid = threadIdx.x;
  const int w = tid >> 6, lane = tid & 63;
  const int qw = w & 1, mw = w >> 1;              // 2 q-waves x 4 m-groups
  const int l31 = lane & 31, l5 = lane >> 5;
  const int nsub = (mw < 3) ? 3 : 2;              // msub per wave (3/3/3/2)

  const f16* Ab = Apan + (long long)((b * 2 + ct) * 64) * A_TILE;
  const float4* tb = tab4 + (long long)b * NN;

  // stage (En,E2) table
#pragma unroll
  for (int i = 0; i < 4; ++i) {
    int idx = i * 512 + tid;
    float4 v = tb[idx];
    Etab[idx] = make_float2(v.x, v.y);
  }

  // per-thread B-column params (q fixed for whole kernel)
  const int qb = tid & 127, kg = tid >> 7;        // builder coords
  const float fq = f[b * NN + qt * 128 + qb];
  const float4 qt4 = tb[qt * 128 + qb];
  const float Rq = qt4.z, Sq = qt4.w;
  const float thrE = __expf(-fq - maxf[b]);       // pos <=> En >= thrE
  const bool do_store = ((qb >> 5) & 1) == ct;    // 32/64 lanes: balanced halves

  f32x16 acc[3][2];
#pragma unroll
  for (int j = 0; j < 3; ++j)
#pragma unroll
    for (int nf = 0; nf < 2; ++nf)
#pragma unroll
      for (int z = 0; z < 16; ++z) acc[j][nf][z] = 0.f;

  auto stageA = [&](int ks, int bsel) {
    const f16* a = Ab + (long long)ks * A_TILE;
    f16* l = Abuf[bsel];
#pragma unroll
    for (int i = 0; i < 3; ++i) {
      int ch = i * 512 + tid;                     // 1408 real chunks of 16 B
      if (ch < 1408) gl_lds16(a + ch * 8, l + ch * 8);
      else           gl_lds16(a + (ch - 1408) * 8, Dpad + (ch - 1408) * 8);
    }
  };
  auto buildB = [&](int ksn, int bsel) {
    const float4* ep = (const float4*)&Etab[ksn * 32 + kg * 8];   // broadcast
    float4 e0 = ep[0], e1 = ep[1], e2 = ep[2], e3 = ep[3];
    float En[8] = {e0.x, e0.z, e1.x, e1.z, e2.x, e2.z, e3.x, e3.z};
    float E2[8] = {e0.y, e0.w, e1.y, e1.w, e2.y, e2.w, e3.y, e3.w};
    f16x8 v8;
    float vf[8];
#pragma unroll
    for (int u = 0; u < 8; ++u) {
      bool pos = En[u] >= thrE;
      float val = (pos ? En[u] : E2[u]) * (pos ? Rq : Sq);
      vf[u] = val;
      v8[u] = (f16)val;
    }
    *(f16x8*)&Bbuf[bsel][kg * 1024 + qb * 8] = v8;
    if (do_store) {                // every wave: 8 stores, 32 lanes active
      long long nb = (long long)(b * 2048 + ksn * 32 + kg * 8) * 2048 + qt * 128 + qb;
#pragma unroll
      for (int u = 0; u < 8; ++u) att[nb + (long long)u * 2048] = vf[u];
    }
  };
  auto compute = [&](int bsel) {
    const f16* A = Abuf[bsel];
    const f16* Bt = Bbuf[bsel];
#pragma unroll
    for (int kc = 0; kc < 2; ++kc) {
      f16x8 bv[2];
#pragma unroll
      for (int nf = 0; nf < 2; ++nf)
        bv[nf] = *(const f16x8*)&Bt[kc * 2048 + l5 * 1024 + (qw * 64 + nf * 32 + l31) * 8];
#pragma unroll
      for (int j = 0; j < 3; ++j) {
        if (j < nsub) {                           // wave-uniform
          int ms = mw * 3 + j;
          f16x8 av = *(const f16x8*)&A[kc * 5632 + ms * 512 + l5 * 256 + l31 * 8];
#pragma unroll
          for (int nf = 0; nf < 2; ++nf)
            acc[j][nf] = __builtin_amdgcn_mfma_f32_32x32x16_f16(av, bv[nf], acc[j][nf], 0, 0, 0);
        }
      }
    }
  };

  // prologue: tiles 0,1 staged (dbuf full); B0 built; one full drain
  stageA(0, 0);
  stageA(1, 1);
  __syncthreads();                 // drains everything (one-time)
  buildB(0, 0);                    // Bbuf[0] + S(0) stores (float onward)
  asm volatile("s_waitcnt lgkmcnt(0)" ::: "memory");
  __builtin_amdgcn_s_barrier();
  __builtin_amdgcn_sched_barrier(0);

  // main loop. Phase 1: compute(ks). Mid-barrier (read-refill separation).
  // Phase 2: stageA(ks+2) into the just-freed buffer + buildB(ks+1).
  // vmcnt(19) <=> L(ks+2) from LAST iter retired; newest S+L+S may float.
  for (int ks = 0; ks < 62; ++ks) {
    compute(ks & 1);
    asm volatile("s_waitcnt lgkmcnt(0)" ::: "memory");   // insurance: reads done
    __builtin_amdgcn_s_barrier();                        // all waves done reading
    __builtin_amdgcn_sched_barrier(0);                   // pin gl_lds below barrier
    stageA(ks + 2, ks & 1);
    buildB(ks + 1, (ks + 1) & 1);
    asm volatile("s_waitcnt vmcnt(19) lgkmcnt(0)" ::: "memory");
    __builtin_amdgcn_s_barrier();
    __builtin_amdgcn_sched_barrier(0);
  }
  // epilogue: tiles 62, 63 (no further staging)
  compute(0);                       // 62&1=0
  buildB(63, 1);
  asm volatile("s_waitcnt vmcnt(16) lgkmcnt(0)" ::: "memory");  // L(63) retired
  __builtin_amdgcn_s_barrier();
  __builtin_amdgcn_sched_barrier(0);
  compute(1);                       // tile 63

  // epilogue: 32x32 C/D: col(q)=lane&31, row(m)=(reg&3)+8*(reg>>2)+4*(lane>>5)
  float* ob = out + (long long)b * COUT * NN * LL;
#pragma unroll
  for (int j = 0; j < 3; ++j) {
    if (j < nsub) {
#pragma unroll
      for (int rq = 0; rq < 4; ++rq) {
#pragma unroll
        for (int r = 0; r < 4; ++r) {
          int row = r + rq * 8 + l5 * 4;
          int m = ct * BM + (mw * 3 + j) * 32 + row;
          int c = m / 11, l2 = m - c * 11;
#pragma unroll
          for (int nf = 0; nf < 2; ++nf) {
            int q = qt * BN + qw * 64 + nf * 32 + l31;
            ob[((long long)c * NN + q) * LL + l2] = acc[j][nf][rq * 4 + r];
          }
        }
      }
    }
  }
}

// ---------------------------------------------------------------------------
extern "C" void kernel_launch(void* const* d_in, const int* in_sizes, int n_in,
                              void* d_out, int out_size, void* d_ws, size_t ws_size,
                              hipStream_t stream) {
  const float* x  = (const float*)d_in[0];
  const float* w0 = (const float*)d_in[1];
  const float* b0 = (const float*)d_in[2];
  const float* w1 = (const float*)d_in[3];

  float* fbuf = (float*)d_ws;                                   // 16384 f
  float* maxf = fbuf + BB * NN;                                 // 8 f
  float4* tab4 = (float4*)((char*)d_ws + WS_TAB_OFF);           // 16384 float4
  unsigned int* w0pk_g = (unsigned int*)((char*)d_ws + WS_W0PK_OFF);  // 24 KB
  f16* Apan = (f16*)((char*)d_ws + WS_APAN_OFF);                // 23.07 MB

  float* hp  = (float*)d_out;
  float* att = hp + HP_SIZE;

  k_pack<<<dim3(24), dim3(256), 0, stream>>>(w0, w0pk_g);
  k_conv<<<dim3(BB * 256), dim3(512), 0, stream>>>(x, w0pk_g, b0, w1, Apan, fbuf);
  k_maxf<<<dim3(BB), dim3(256), 0, stream>>>(fbuf, maxf);
  k_rowsum<<<dim3(BB * 512), dim3(256), 0, stream>>>(fbuf, maxf, tab4);
  k_gemm<<<dim3(256), dim3(512), 0, stream>>>(Apan, fbuf, maxf, tab4, att, hp);
}

// Round 13
// 158.734 us; speedup vs baseline: 3.5478x; 3.5478x over previous
//
#include <hip/hip_runtime.h>

// Problem constants (fixed by setup_inputs)
#define BB 8
#define CIN 64
#define COUT 64
#define NN 2048
#define TT 13
#define KTT 3
#define LL 11
#define CL 704                         // COUT*LL
#define HP_SIZE 11534336LL             // B*COUT*N*L

// ws layout (bytes): fbuf 65536 | maxf 32 | tab4 262144 | w0pk 24576 | Apan
#define WS_TAB_OFF 65568ULL
#define WS_W0PK_OFF 327712ULL
#define WS_APAN_OFF 352288ULL

typedef _Float16 f16;
typedef __attribute__((ext_vector_type(8))) _Float16 f16x8;
typedef __attribute__((ext_vector_type(2))) _Float16 f16x2;
typedef __attribute__((ext_vector_type(4))) float f32x4;

__device__ __forceinline__ unsigned int pk16(float a, float b) {
  f16 ha = (f16)a, hb = (f16)b;                    // RTN converts
  unsigned short ua = __builtin_bit_cast(unsigned short, ha);
  unsigned short ub = __builtin_bit_cast(unsigned short, hb);
  return (unsigned int)ua | ((unsigned int)ub << 16);
}
__device__ __forceinline__ f16x2 as_h2(unsigned int u) {
  return __builtin_bit_cast(f16x2, u);
}

// ---------------------------------------------------------------------------
// Kernel 0: pack w0 into ci-pair v2f16 form, once.
// ---------------------------------------------------------------------------
__global__ __launch_bounds__(256) void k_pack(const float* __restrict__ w0,
                                              unsigned int* __restrict__ w0pk_g) {
  int tid = blockIdx.x * 256 + threadIdx.x;        // 6144 total
  int c = tid & 63, r = tid >> 6;                  // r = cip*3+kt, 0..95
  int kt = r % 3, cip = r / 3;
  float ev = w0[c * 192 + cip * 6 + kt];
  float od = w0[c * 192 + cip * 6 + 3 + kt];
  w0pk_g[r * 64 + c] = pk16(ev, od);
}

// ---------------------------------------------------------------------------
// Kernel 1: conv0 via v_dot2_f32_f16 -> fp16 A panels (16-row-frag layout) + f.
// A panel: Apan[(b*11+mt)*64+ks] tile of 2048 f16 = [fr4][lane64][kk8];
// lane = kgrp*16 + row16; element = h[n = ks*32+kgrp*8+kk][m = mt*64+fr*16+row16]
// ---------------------------------------------------------------------------
__global__ __launch_bounds__(512, 4) void k_conv(
    const float* __restrict__ x, const unsigned int* __restrict__ w0pk_g,
    const float* __restrict__ b0, const float* __restrict__ w1,
    f16* __restrict__ Apan, float* __restrict__ f) {
  __shared__ unsigned int w0pk[96 * 64];       // 24 KB
  __shared__ unsigned int xspk[32 * 8 * 16];   // 16 KB
  __shared__ f16 As[704 * 10];                 // 14 KB
  const int tid = threadIdx.x;
  const int b = blockIdx.x >> 8;
  const int n0 = (blockIdx.x & 255) << 3;

#pragma unroll
  for (int i = 0; i < 12; ++i) w0pk[i * 512 + tid] = w0pk_g[i * 512 + tid];

#pragma unroll
  for (int i = 0; i < 7; ++i) {
    int task = i * 512 + tid;                  // 3328 total
    if (task < 3328) {
      int cip = task / 104, rem = task - cip * 104;
      long long base = (long long)(b * 64 + 2 * cip) * 26624 + n0 * 13 + rem;
      float ev = x[base];
      float od = x[base + 26624];
      int n = rem / 13, t = rem - n * 13;
      xspk[(cip * 8 + n) * 16 + t] = pk16(ev, od);
    }
  }
  __syncthreads();

  const int c = tid & 63, w = tid >> 6;
  float acc[11];
  const float bias = b0[c];
#pragma unroll
  for (int l = 0; l < 11; ++l) acc[l] = bias;

  for (int cip = 0; cip < 32; ++cip) {
    const unsigned int* xr = &xspk[(cip * 8 + w) * 16];
    uint4 xa = *(const uint4*)xr;
    uint4 xb = *(const uint4*)(xr + 4);
    uint4 xc = *(const uint4*)(xr + 8);
    unsigned int x13[13] = {xa.x, xa.y, xa.z, xa.w, xb.x, xb.y, xb.z, xb.w,
                            xc.x, xc.y, xc.z, xc.w, xr[12]};
    f16x2 wk0 = as_h2(w0pk[(cip * 3 + 0) * 64 + c]);
    f16x2 wk1 = as_h2(w0pk[(cip * 3 + 1) * 64 + c]);
    f16x2 wk2 = as_h2(w0pk[(cip * 3 + 2) * 64 + c]);
#pragma unroll
    for (int l = 0; l < 11; ++l) {
      acc[l] = __builtin_amdgcn_fdot2(as_h2(x13[l]), wk0, acc[l], false);
      acc[l] = __builtin_amdgcn_fdot2(as_h2(x13[l + 1]), wk1, acc[l], false);
      acc[l] = __builtin_amdgcn_fdot2(as_h2(x13[l + 2]), wk2, acc[l], false);
    }
  }

  float p = 0.f;
#pragma unroll
  for (int l = 0; l < 11; ++l) p = fmaf(acc[l], w1[c * 11 + l], p);
#pragma unroll
  for (int off = 32; off; off >>= 1) p += __shfl_xor(p, off, 64);
  if (c == 0) f[b * 2048 + n0 + w] = p;

#pragma unroll
  for (int l = 0; l < 11; ++l) As[(c * 11 + l) * 10 + w] = (f16)acc[l];
  __syncthreads();

  // panel write: this block covers ks, kgrp, kk = 0..7 (= w dim in As)
  const int ks = n0 >> 5, kgrp = (n0 >> 3) & 3;
  const unsigned int* As32 = (const unsigned int*)As;
#pragma unroll
  for (int i = 0; i < 2; ++i) {
    int m = i * 512 + tid;
    if (m < 704) {
      uint4 v;
      v.x = As32[m * 5 + 0];
      v.y = As32[m * 5 + 1];
      v.z = As32[m * 5 + 2];
      v.w = As32[m * 5 + 3];
      int mt = m >> 6, fr = (m >> 4) & 3, r16 = m & 15;
      long long base = ((long long)(b * 11 + mt) * 64 + ks) * 2048 +
                       fr * 512 + (kgrp * 16 + r16) * 8;
      *(uint4*)&Apan[base] = v;
    }
  }
}

// ---------------------------------------------------------------------------
// Kernel 2: per-batch max of f
// ---------------------------------------------------------------------------
__global__ __launch_bounds__(256) void k_maxf(const float* __restrict__ f,
                                              float* __restrict__ maxf) {
  const int b = blockIdx.x, tid = threadIdx.x;
  float m = -1e30f;
  for (int i = tid; i < 2048; i += 256) m = fmaxf(m, f[b * 2048 + i]);
#pragma unroll
  for (int off = 32; off; off >>= 1) m = fmaxf(m, __shfl_xor(m, off, 64));
  __shared__ float red[4];
  if ((tid & 63) == 0) red[tid >> 6] = m;
  __syncthreads();
  if (tid == 0) maxf[b] = fmaxf(fmaxf(red[0], red[1]), fmaxf(red[2], red[3]));
}

// ---------------------------------------------------------------------------
// Kernel 3: softmax row sums + exp-factor table tab4 = (En, E2n, Rq, Sq).
// att[n][q] = max(En_n*Rq_q, E2n_n*Sq_q)  (exact: pos-branch wins iff s>=0)
// ---------------------------------------------------------------------------
__global__ __launch_bounds__(256) void k_rowsum(const float* __restrict__ f,
                                                const float* __restrict__ maxf,
                                                float4* __restrict__ tab4) {
  __shared__ float fs[2048];
  const int b = blockIdx.x >> 9;
  const int q0 = (blockIdx.x & 511) << 2;
  const int tid = threadIdx.x;
#pragma unroll
  for (int i = 0; i < 8; ++i) fs[i * 256 + tid] = f[b * 2048 + i * 256 + tid];
  __syncthreads();
  const int lane = tid & 63, wid = tid >> 6;
  const int q = q0 + wid;
  const float fq = fs[q];
  const float mb = maxf[b];
  float t = fq + mb;
  const float m = t >= 0.f ? t : 0.2f * t;
  float sum = 0.f;
  for (int j = lane; j < 2048; j += 64) {
    float v = fq + fs[j];
    v = v >= 0.f ? v : 0.2f * v;
    sum += __expf(v - m);
  }
#pragma unroll
  for (int off = 32; off; off >>= 1) sum += __shfl_xor(sum, off, 64);
  if (lane == 0) {
    float rq = 1.0f / sum;
    float En = __expf(fq - mb);
    float E2 = __expf(0.2f * fq);
    float Rq = t >= 0.f ? rq : rq * __expf(0.8f * t);
    float Sq = rq * __expf(0.2f * fq - m);
    tab4[b * 2048 + q] = make_float4(En, E2, Rq, Sq);
  }
}

// ---------------------------------------------------------------------------
// Kernel 4: barrier-free 16x16x32 fp16 MFMA GEMM.
// A: direct global->reg dwordx4 (panel layout == fragment layout), pipelined
//    1 tile ahead; L2-resident via XCD grouping (p = g + 88*qt, 88%8==0 ->
//    all 8 qt-siblings of a (b,mt) A-slice land on one XCD).
// B: built in registers from LDS Etab (read-only after one prologue barrier):
//    att[n][q] = max(En*Rq, E2*Sq). No ds_write, no per-tile barrier.
// Block: 256 thr = 4 q-waves; wave = 4 mfrag (64 rows) x 4 nf (64 q).
// acc = 4x4 f32x4 = 64 VGPR. Fused balanced att stores ((ks*11)>>6 == mt).
// ---------------------------------------------------------------------------
__global__ __launch_bounds__(256, 3) void k_gemm(const f16* __restrict__ Apan,
                                                 const float4* __restrict__ tab4,
                                                 float* __restrict__ att,
                                                 float* __restrict__ out) {
  __shared__ __align__(16) float2 Etab[2048];   // 16 KB, read-only after stage

  const int p = blockIdx.x;
  const int g = p % 88, qt = p / 88;
  const int b = g / 11, mt = g % 11;

  const int tid = threadIdx.x;
  const int qw = tid >> 6, lane = tid & 63;
  const int l15 = lane & 15, l4 = lane >> 4;

  const f16* Ab = Apan + ((long long)(b * 11 + mt) * 64) * 2048 + lane * 8;
  const float4* tb = tab4 + (long long)b * NN;

  // stage Etab (16 KB)
#pragma unroll
  for (int i = 0; i < 8; ++i) {
    int idx = i * 256 + tid;
    float4 v = tb[idx];
    Etab[idx] = make_float2(v.x, v.y);
  }
  // per-nf q-side factors (q fixed per lane per nf)
  const int q0 = qt * 256 + qw * 64 + l15;
  float Rq0, Sq0, Rq1, Sq1, Rq2, Sq2, Rq3, Sq3;
  { float4 t4 = tb[q0];      Rq0 = t4.z; Sq0 = t4.w; }
  { float4 t4 = tb[q0 + 16]; Rq1 = t4.z; Sq1 = t4.w; }
  { float4 t4 = tb[q0 + 32]; Rq2 = t4.z; Sq2 = t4.w; }
  { float4 t4 = tb[q0 + 48]; Rq3 = t4.z; Sq3 = t4.w; }
  __syncthreads();   // Etab ready; ONLY barrier in the kernel

  f32x4 acc[4][4];
#pragma unroll
  for (int fr = 0; fr < 4; ++fr)
#pragma unroll
    for (int nf = 0; nf < 4; ++nf) acc[fr][nf] = (f32x4){0.f, 0.f, 0.f, 0.f};

  // A-load pipeline: current tile in c0..c3, next prefetched into n0..n3
  f16x8 c0 = *(const f16x8*)(Ab);
  f16x8 c1 = *(const f16x8*)(Ab + 512);
  f16x8 c2 = *(const f16x8*)(Ab + 1024);
  f16x8 c3 = *(const f16x8*)(Ab + 1536);

  for (int ks = 0; ks < 64; ++ks) {
    f16x8 n0 = c0, n1 = c1, n2 = c2, n3 = c3;
    if (ks < 63) {
      const f16* at = Ab + (ks + 1) * 2048;
      n0 = *(const f16x8*)(at);
      n1 = *(const f16x8*)(at + 512);
      n2 = *(const f16x8*)(at + 1024);
      n3 = *(const f16x8*)(at + 1536);
    }
    // lane's 8 n-values of the exp-factor table (broadcast within 16-group)
    const int nb = ks * 32 + l4 * 8;
    const float4* ep = (const float4*)&Etab[nb];
    float4 e0 = ep[0], e1 = ep[1], e2 = ep[2], e3 = ep[3];
    float En[8] = {e0.x, e0.z, e1.x, e1.z, e2.x, e2.z, e3.x, e3.z};
    float E2[8] = {e0.y, e0.w, e1.y, e1.w, e2.y, e2.w, e3.y, e3.w};
    const bool owned = ((ks * 11) >> 6) == mt;   // block-uniform
    const long long abase = ((long long)(b * 2048 + nb)) * 2048 + q0;

#pragma unroll
    for (int nf = 0; nf < 4; ++nf) {
      const float Rq = nf == 0 ? Rq0 : nf == 1 ? Rq1 : nf == 2 ? Rq2 : Rq3;
      const float Sq = nf == 0 ? Sq0 : nf == 1 ? Sq1 : nf == 2 ? Sq2 : Sq3;
      f16x8 bv;
      float vf[8];
#pragma unroll
      for (int u = 0; u < 8; ++u) {
        float val = fmaxf(En[u] * Rq, E2[u] * Sq);
        vf[u] = val;
        bv[u] = (f16)val;
      }
      if (owned) {
        float* ap = att + abase + nf * 16;
#pragma unroll
        for (int u = 0; u < 8; ++u) ap[(long long)u * 2048] = vf[u];
      }
      acc[0][nf] = __builtin_amdgcn_mfma_f32_16x16x32_f16(c0, bv, acc[0][nf], 0, 0, 0);
      acc[1][nf] = __builtin_amdgcn_mfma_f32_16x16x32_f16(c1, bv, acc[1][nf], 0, 0, 0);
      acc[2][nf] = __builtin_amdgcn_mfma_f32_16x16x32_f16(c2, bv, acc[2][nf], 0, 0, 0);
      acc[3][nf] = __builtin_amdgcn_mfma_f32_16x16x32_f16(c3, bv, acc[3][nf], 0, 0, 0);
    }
    c0 = n0; c1 = n1; c2 = n2; c3 = n3;
  }

  // epilogue: C/D layout col(q)=lane&15, row(m)=(lane>>4)*4+r
  float* ob = out + (long long)b * COUT * NN * LL;
#pragma unroll
  for (int fr = 0; fr < 4; ++fr) {
#pragma unroll
    for (int r = 0; r < 4; ++r) {
      int m = mt * 64 + fr * 16 + l4 * 4 + r;
      int c = m / 11, l2 = m - c * 11;
      float* orow = ob + (long long)c * NN * LL + l2;
#pragma unroll
      for (int nf = 0; nf < 4; ++nf) {
        int q = q0 + nf * 16;
        orow[(long long)q * LL] = acc[fr][nf][r];
      }
    }
  }
}

// ---------------------------------------------------------------------------
extern "C" void kernel_launch(void* const* d_in, const int* in_sizes, int n_in,
                              void* d_out, int out_size, void* d_ws, size_t ws_size,
                              hipStream_t stream) {
  const float* x  = (const float*)d_in[0];
  const float* w0 = (const float*)d_in[1];
  const float* b0 = (const float*)d_in[2];
  const float* w1 = (const float*)d_in[3];

  float* fbuf = (float*)d_ws;                                   // 16384 f
  float* maxf = fbuf + BB * NN;                                 // 8 f
  float4* tab4 = (float4*)((char*)d_ws + WS_TAB_OFF);           // 16384 float4
  unsigned int* w0pk_g = (unsigned int*)((char*)d_ws + WS_W0PK_OFF);  // 24 KB
  f16* Apan = (f16*)((char*)d_ws + WS_APAN_OFF);                // 23.07 MB

  float* hp  = (float*)d_out;
  float* att = hp + HP_SIZE;

  k_pack<<<dim3(24), dim3(256), 0, stream>>>(w0, w0pk_g);
  k_conv<<<dim3(BB * 256), dim3(512), 0, stream>>>(x, w0pk_g, b0, w1, Apan, fbuf);
  k_maxf<<<dim3(BB), dim3(256), 0, stream>>>(fbuf, maxf);
  k_rowsum<<<dim3(BB * 512), dim3(256), 0, stream>>>(fbuf, maxf, tab4);
  k_gemm<<<dim3(704), dim3(256), 0, stream>>>(Apan, tab4, att, hp);
}